// Round 6
// baseline (223.386 us; speedup 1.0000x reference)
//
#include <hip/hip_runtime.h>
#include <hip/hip_bf16.h>
#include <hip/hip_cooperative_groups.h>

namespace cg = cooperative_groups;

#define NB 4
#define NN 256
#define ND 256
#define NK 1024
#define LOG2E 1.4426950408889634f

// ---- fallback (3-kernel) partition: exact round-4 config, verified ----
#define FB_EDGE_BLOCKS 800
#define FB_TRI_BLOCKS 1216
#define FB_G2_BLOCKS 32
#define FB_LSE_BLOCKS (FB_EDGE_BLOCKS + FB_TRI_BLOCKS)   // 2016
#define FB_K2_BLOCKS (FB_LSE_BLOCKS + FB_G2_BLOCKS)      // 2048

typedef __bf16 bf16x8 __attribute__((ext_vector_type(8)));
typedef float f32x4 __attribute__((ext_vector_type(4)));
typedef float f32x2 __attribute__((ext_vector_type(2)));

// ---- fp8 helpers (OCP e4m3; encoder/decoder are the same HW cvt pair) ----
__device__ __forceinline__ void dot4_fp8(unsigned a, unsigned b,
                                         float& s0, float& s1) {
  const f32x2 a0 = __builtin_amdgcn_cvt_pk_f32_fp8(a, false);
  const f32x2 a1 = __builtin_amdgcn_cvt_pk_f32_fp8(a, true);
  const f32x2 b0 = __builtin_amdgcn_cvt_pk_f32_fp8(b, false);
  const f32x2 b1 = __builtin_amdgcn_cvt_pk_f32_fp8(b, true);
  s0 = fmaf(a0[0], b0[0], s0);
  s1 = fmaf(a0[1], b0[1], s1);
  s0 = fmaf(a1[0], b1[0], s0);
  s1 = fmaf(a1[1], b1[1], s1);
}

__device__ __forceinline__ void tdot4_fp8(unsigned a, unsigned b, unsigned c,
                                          float& s0, float& s1) {
  const f32x2 a0 = __builtin_amdgcn_cvt_pk_f32_fp8(a, false);
  const f32x2 a1 = __builtin_amdgcn_cvt_pk_f32_fp8(a, true);
  const f32x2 b0 = __builtin_amdgcn_cvt_pk_f32_fp8(b, false);
  const f32x2 b1 = __builtin_amdgcn_cvt_pk_f32_fp8(b, true);
  const f32x2 c0 = __builtin_amdgcn_cvt_pk_f32_fp8(c, false);
  const f32x2 c1 = __builtin_amdgcn_cvt_pk_f32_fp8(c, true);
  s0 = fmaf(a0[0] * b0[0], c0[0], s0);
  s1 = fmaf(a0[1] * b0[1], c0[1], s1);
  s0 = fmaf(a1[0] * b1[0], c1[0], s0);
  s1 = fmaf(a1[1] * b1[1], c1[1], s1);
}

__device__ __forceinline__ float wave_reduce(float s) {
#pragma unroll
  for (int m = 32; m >= 1; m >>= 1) s += __shfl_xor(s, m, 64);
  return s;
}

// GEMM tile body: computes 16x64 tile (m-tile t>>4, n-group t&15), E8=fp8(exp(beta*h))
__device__ __forceinline__ void gemm_tile(
    const float* __restrict__ A, const float* __restrict__ P, const float c,
    unsigned char* __restrict__ E8, const int t, const int w, const int lane) {
  const int m0 = (t >> 4) * 16;
  const int n0 = (t & 15) * 64 + w * 16;
  const int r15 = lane & 15;
  const int g4 = lane >> 4;
  const int arow = m0 + r15;
  const int bcol = n0 + r15;

  f32x4 acc = {0.f, 0.f, 0.f, 0.f};
#pragma unroll
  for (int kk = 0; kk < ND; kk += 32) {
    const int kb = kk + g4 * 8;  // same (group,elem)->k map for A and B => layout-safe
    const float* ap = A + arow * ND + kb;
    const float4 a0 = *(const float4*)ap;
    const float4 a1 = *(const float4*)(ap + 4);
    const float* pp = P + kb * NK + bcol;
    bf16x8 af, bfr;
    af[0] = (__bf16)a0.x; af[1] = (__bf16)a0.y; af[2] = (__bf16)a0.z; af[3] = (__bf16)a0.w;
    af[4] = (__bf16)a1.x; af[5] = (__bf16)a1.y; af[6] = (__bf16)a1.z; af[7] = (__bf16)a1.w;
    bfr[0] = (__bf16)pp[0 * NK]; bfr[1] = (__bf16)pp[1 * NK];
    bfr[2] = (__bf16)pp[2 * NK]; bfr[3] = (__bf16)pp[3 * NK];
    bfr[4] = (__bf16)pp[4 * NK]; bfr[5] = (__bf16)pp[5 * NK];
    bfr[6] = (__bf16)pp[6 * NK]; bfr[7] = (__bf16)pp[7 * NK];
    acc = __builtin_amdgcn_mfma_f32_16x16x32_bf16(af, bfr, acc, 0, 0, 0);
  }
#pragma unroll
  for (int r = 0; r < 4; ++r) {
    const int orow = m0 + g4 * 4 + r;   // C/D: col=lane&15, row=(lane>>4)*4+r (HW-verified)
    const float e = exp2f(c * acc[r]);
    const int p = __builtin_amdgcn_cvt_pk_fp8_f32(e, e, 0, false);
    E8[orow * NK + bcol] = (unsigned char)(p & 0xff);
  }
}

__device__ __forceinline__ float edge_sum(
    const unsigned char* __restrict__ E8, const int* __restrict__ edges,
    const int m_edge, const int first, const int stride, const int lane) {
  const int ntask = NB * m_edge;
  float lsum = 0.0f;
  for (int task = first; task < ntask; task += stride) {
    const int b = task / m_edge;
    const int e = task - b * m_edge;
    const int v0 = edges[2 * e];
    const int v1 = edges[2 * e + 1];
    const size_t base = ((size_t)b << 18);
    const uint4 ua = ((const uint4*)(E8 + base + ((size_t)v0 << 10)))[lane];
    const uint4 ub = ((const uint4*)(E8 + base + ((size_t)v1 << 10)))[lane];
    float s0 = 0.f, s1 = 0.f;
    dot4_fp8(ua.x, ub.x, s0, s1);
    dot4_fp8(ua.y, ub.y, s0, s1);
    dot4_fp8(ua.z, ub.z, s0, s1);
    dot4_fp8(ua.w, ub.w, s0, s1);
    lsum += __logf(wave_reduce(s0 + s1));
  }
  return lsum;
}

__device__ __forceinline__ float tri_sum(
    const unsigned char* __restrict__ E8, const int* __restrict__ tris,
    const int m_tri, const int first, const int stride, const int lane) {
  const int ntask = NB * m_tri;
  float lsum = 0.0f;
  for (int task = first; task < ntask; task += stride) {
    const int b = task / m_tri;
    const int e = task - b * m_tri;
    const int v0 = tris[3 * e];
    const int v1 = tris[3 * e + 1];
    const int v2 = tris[3 * e + 2];
    const size_t base = ((size_t)b << 18);
    const uint4 ua = ((const uint4*)(E8 + base + ((size_t)v0 << 10)))[lane];
    const uint4 ub = ((const uint4*)(E8 + base + ((size_t)v1 << 10)))[lane];
    const uint4 uc = ((const uint4*)(E8 + base + ((size_t)v2 << 10)))[lane];
    float s0 = 0.f, s1 = 0.f;
    tdot4_fp8(ua.x, ub.x, uc.x, s0, s1);
    tdot4_fp8(ua.y, ub.y, uc.y, s0, s1);
    tdot4_fp8(ua.z, ub.z, uc.z, s0, s1);
    tdot4_fp8(ua.w, ub.w, uc.w, s0, s1);
    lsum += __logf(wave_reduce(s0 + s1));
  }
  return lsum;
}

// ================= cooperative single-kernel path =================
__global__ __launch_bounds__(256, 4) void fused_all_kernel(
    const float* __restrict__ A, const float* __restrict__ P,
    const float* __restrict__ beta,
    const int* __restrict__ edges, const int m_edge,
    const int* __restrict__ tris, const int m_tri,
    unsigned char* __restrict__ E8,
    float* __restrict__ pl, float* __restrict__ pg2,
    float* __restrict__ out, const int ns,
    const int edgeB, const int triB, const int nblk) {
  cg::grid_group grid = cg::this_grid();
  __shared__ float sp[4];
  const int lane = threadIdx.x & 63;
  const int w = threadIdx.x >> 6;
  const int bid = blockIdx.x;
  const int lseB = edgeB + triB;
  const float c = beta[0] * LOG2E;

  // stage A: grid-stride over the 1024 GEMM tiles
  for (int t = bid; t < 1024; t += nblk) gemm_tile(A, P, c, E8, t, w, lane);

  grid.sync();

  // stage B
  if (bid < edgeB) {
    const float lsum = edge_sum(E8, edges, m_edge, bid * 4 + w, edgeB * 4, lane);
    if (lane == 0) sp[w] = lsum;
    __syncthreads();
    if (threadIdx.x == 0) pl[bid] = sp[0] + sp[1] + sp[2] + sp[3];
  } else if (bid < lseB) {
    const float lsum = tri_sum(E8, tris, m_tri, (bid - edgeB) * 4 + w, triB * 4, lane);
    if (lane == 0) sp[w] = lsum;
    __syncthreads();
    if (threadIdx.x == 0) pl[bid] = sp[0] + sp[1] + sp[2] + sp[3];
  } else if (bid < lseB + 16) {
    const int gi = bid - lseB;
    float s = 0.0f;
    for (int i = gi * 256 + threadIdx.x; i < 65536; i += 16 * 256) {
      const float4 v = ((const float4*)A)[i];
      s += v.x * v.x + v.y * v.y + v.z * v.z + v.w * v.w;
    }
    s = wave_reduce(s);
    if (lane == 0) sp[w] = s;
    __syncthreads();
    if (threadIdx.x == 0) pg2[gi] = sp[0] + sp[1] + sp[2] + sp[3];
  }

  grid.sync();

  // stage C: block 0 final reduce
  if (bid == 0) {
    __shared__ float sa[4], sb[4];
    float sl = 0.f, sg = 0.f;
    for (int i = threadIdx.x; i < lseB; i += 256) sl += pl[i];
    if (threadIdx.x < 16) sg = pg2[threadIdx.x];
    sl = wave_reduce(sl);
    sg = wave_reduce(sg);
    if (lane == 0) { sa[w] = sl; sb[w] = sg; }
    __syncthreads();
    if (threadIdx.x == 0) {
      const float L = sa[0] + sa[1] + sa[2] + sa[3];
      const float Gg = sb[0] + sb[1] + sb[2] + sb[3];
      const float ep = -(1.0f / (beta[0] * (float)ns)) * L;
      out[0] = (ep - 2.0f * Gg) / (float)(NB * NN);
    }
  }
}

// ================= fallback 3-kernel path (round-4 verified) =================
__global__ __launch_bounds__(256) void gemm_exp_kernel(
    const float* __restrict__ A, const float* __restrict__ P,
    const float* __restrict__ beta, unsigned char* __restrict__ E8) {
  const int lane = threadIdx.x & 63;
  const int w = threadIdx.x >> 6;
  const int t = (blockIdx.x << 4) | blockIdx.y;   // m-tile | n-group
  gemm_tile(A, P, beta[0] * LOG2E, E8, t, w, lane);
}

__global__ __launch_bounds__(256, 8) void fused_simplex_kernel(
    const unsigned char* __restrict__ E8,
    const int* __restrict__ edges, const int m_edge,
    const int* __restrict__ tris, const int m_tri,
    const float* __restrict__ g,
    float* __restrict__ pl, float* __restrict__ pg2) {
  __shared__ float sp[4];
  const int lane = threadIdx.x & 63;
  const int w = threadIdx.x >> 6;
  const int bid = blockIdx.x;

  if (bid < FB_EDGE_BLOCKS) {
    const float lsum = edge_sum(E8, edges, m_edge, bid * 4 + w, FB_EDGE_BLOCKS * 4, lane);
    if (lane == 0) sp[w] = lsum;
    __syncthreads();
    if (threadIdx.x == 0) pl[bid] = sp[0] + sp[1] + sp[2] + sp[3];
  } else if (bid < FB_LSE_BLOCKS) {
    const float lsum = tri_sum(E8, tris, m_tri, (bid - FB_EDGE_BLOCKS) * 4 + w,
                               FB_TRI_BLOCKS * 4, lane);
    if (lane == 0) sp[w] = lsum;
    __syncthreads();
    if (threadIdx.x == 0) pl[bid] = sp[0] + sp[1] + sp[2] + sp[3];
  } else {
    const int gi = bid - FB_LSE_BLOCKS;
    float s = 0.0f;
    for (int i = gi * 256 + threadIdx.x; i < 65536; i += FB_G2_BLOCKS * 256) {
      const float4 v = ((const float4*)g)[i];
      s += v.x * v.x + v.y * v.y + v.z * v.z + v.w * v.w;
    }
    s = wave_reduce(s);
    if (lane == 0) sp[w] = s;
    __syncthreads();
    if (threadIdx.x == 0) pg2[gi] = sp[0] + sp[1] + sp[2] + sp[3];
  }
}

__global__ __launch_bounds__(256) void final_kernel(
    const float* __restrict__ pl, const float* __restrict__ pg2,
    const float* __restrict__ beta, const int ns, float* __restrict__ out) {
  __shared__ float sa[4], sb[4];
  float sl = 0.f, sg = 0.f;
  for (int i = threadIdx.x; i < FB_LSE_BLOCKS; i += 256) sl += pl[i];
  if (threadIdx.x < FB_G2_BLOCKS) sg = pg2[threadIdx.x];
  sl = wave_reduce(sl);
  sg = wave_reduce(sg);
  const int lane = threadIdx.x & 63;
  const int w = threadIdx.x >> 6;
  if (lane == 0) { sa[w] = sl; sb[w] = sg; }
  __syncthreads();
  if (threadIdx.x == 0) {
    const float L = sa[0] + sa[1] + sa[2] + sa[3];
    const float Gg = sb[0] + sb[1] + sb[2] + sb[3];
    const float ep = -(1.0f / (beta[0] * (float)ns)) * L;
    out[0] = (ep - 2.0f * Gg) / (float)(NB * NN);
  }
}

extern "C" void kernel_launch(void* const* d_in, const int* in_sizes, int n_in,
                              void* d_out, int out_size, void* d_ws, size_t ws_size,
                              hipStream_t stream) {
  const float* g = (const float*)d_in[0];
  const float* patterns = (const float*)d_in[1];
  const float* beta = (const float*)d_in[2];
  const int* edges = (const int*)d_in[3];
  const int* triangles = (const int*)d_in[4];
  int m_edge = in_sizes[3] / 2;   // 16320
  int m_tri = in_sizes[4] / 3;    // 16320
  int ns = m_edge + m_tri;

  // ws: E8 1MB | pl[2048] | pg2[32]
  unsigned char* E8 = (unsigned char*)d_ws;
  float* pl = (float*)((char*)d_ws + (1u << 20));
  float* pg2 = pl + 2048;
  float* out = (float*)d_out;

  // Capture-safe host queries (deterministic per system).
  int dev = 0;
  (void)hipGetDevice(&dev);
  int coop = 0;
  (void)hipDeviceGetAttribute(&coop, hipDeviceAttributeCooperativeLaunch, dev);
  int ncu = 0;
  (void)hipDeviceGetAttribute(&ncu, hipDeviceAttributeMultiprocessorCount, dev);
  int occ = 0;
  (void)hipOccupancyMaxActiveBlocksPerMultiprocessor(
      &occ, (const void*)fused_all_kernel, 256, 0);
  int nblk = (coop && occ > 0 && ncu > 0) ? (occ * ncu) : 0;
  if (nblk > 1024) nblk = 1024;

  if (nblk >= 512) {
    int edgeB = ((nblk - 16) * 2) / 5;
    int triB = nblk - 16 - edgeB;
    void* args[] = {(void*)&g, (void*)&patterns, (void*)&beta,
                    (void*)&edges, (void*)&m_edge,
                    (void*)&triangles, (void*)&m_tri,
                    (void*)&E8, (void*)&pl, (void*)&pg2,
                    (void*)&out, (void*)&ns,
                    (void*)&edgeB, (void*)&triB, (void*)&nblk};
    if (hipLaunchCooperativeKernel((void*)fused_all_kernel, dim3(nblk), dim3(256),
                                   args, 0, stream) == hipSuccess) {
      return;
    }
  }

  // fallback: verified 3-kernel path
  hipLaunchKernelGGL(gemm_exp_kernel, dim3(64, 16), dim3(256), 0, stream,
                     g, patterns, beta, E8);
  hipLaunchKernelGGL(fused_simplex_kernel, dim3(FB_K2_BLOCKS), dim3(256), 0, stream,
                     E8, edges, m_edge, triangles, m_tri, g, pl, pg2);
  hipLaunchKernelGGL(final_kernel, dim3(1), dim3(256), 0, stream,
                     pl, pg2, beta, ns, out);
}

// Round 7
// 83.766 us; speedup vs baseline: 2.6668x; 2.6668x over previous
//
#include <hip/hip_runtime.h>
#include <hip/hip_bf16.h>

#define NB 4
#define NN 256
#define ND 256
#define NK 1024
#define LOG2E 1.4426950408889634f

#define EDGE_BLOCKS 800
#define TRI_BLOCKS 1248
#define K2_BLOCKS (EDGE_BLOCKS + TRI_BLOCKS)   // 2048
#define K1_BLOCKS 1056                          // 1024 gemm tiles + 32 g2
#define REP1 12                                 // K1 internal repeats (measurement)
#define REP2 4                                  // K2 internal repeats (measurement)

typedef __bf16 bf16x8 __attribute__((ext_vector_type(8)));
typedef float f32x4 __attribute__((ext_vector_type(4)));
typedef float f32x2 __attribute__((ext_vector_type(2)));

// ---- fp8 helpers (OCP e4m3; encoder/decoder are the same HW cvt pair) ----
__device__ __forceinline__ void dot4_fp8(unsigned a, unsigned b,
                                         float& s0, float& s1) {
  const f32x2 a0 = __builtin_amdgcn_cvt_pk_f32_fp8(a, false);
  const f32x2 a1 = __builtin_amdgcn_cvt_pk_f32_fp8(a, true);
  const f32x2 b0 = __builtin_amdgcn_cvt_pk_f32_fp8(b, false);
  const f32x2 b1 = __builtin_amdgcn_cvt_pk_f32_fp8(b, true);
  s0 = fmaf(a0[0], b0[0], s0);
  s1 = fmaf(a0[1], b0[1], s1);
  s0 = fmaf(a1[0], b1[0], s0);
  s1 = fmaf(a1[1], b1[1], s1);
}

__device__ __forceinline__ void tdot4_fp8(unsigned a, unsigned b, unsigned c,
                                          float& s0, float& s1) {
  const f32x2 a0 = __builtin_amdgcn_cvt_pk_f32_fp8(a, false);
  const f32x2 a1 = __builtin_amdgcn_cvt_pk_f32_fp8(a, true);
  const f32x2 b0 = __builtin_amdgcn_cvt_pk_f32_fp8(b, false);
  const f32x2 b1 = __builtin_amdgcn_cvt_pk_f32_fp8(b, true);
  const f32x2 c0 = __builtin_amdgcn_cvt_pk_f32_fp8(c, false);
  const f32x2 c1 = __builtin_amdgcn_cvt_pk_f32_fp8(c, true);
  s0 = fmaf(a0[0] * b0[0], c0[0], s0);
  s1 = fmaf(a0[1] * b0[1], c0[1], s1);
  s0 = fmaf(a1[0] * b1[0], c1[0], s0);
  s1 = fmaf(a1[1] * b1[1], c1[1], s1);
}

__device__ __forceinline__ float wave_reduce(float s) {
#pragma unroll
  for (int m = 32; m >= 1; m >>= 1) s += __shfl_xor(s, m, 64);
  return s;
}

// GEMM tile body: 16x64 tile (m-tile t>>4, n-group t&15), E8 = fp8(exp(beta*h))
__device__ __forceinline__ void gemm_tile(
    const float* __restrict__ A, const float* __restrict__ P, const float c,
    unsigned char* __restrict__ E8, const int t, const int w, const int lane) {
  const int m0 = (t >> 4) * 16;
  const int n0 = (t & 15) * 64 + w * 16;
  const int r15 = lane & 15;
  const int g4 = lane >> 4;
  const int arow = m0 + r15;
  const int bcol = n0 + r15;

  f32x4 acc = {0.f, 0.f, 0.f, 0.f};
#pragma unroll
  for (int kk = 0; kk < ND; kk += 32) {
    const int kb = kk + g4 * 8;  // same (group,elem)->k map for A and B => layout-safe
    const float* ap = A + arow * ND + kb;
    const float4 a0 = *(const float4*)ap;
    const float4 a1 = *(const float4*)(ap + 4);
    const float* pp = P + kb * NK + bcol;
    bf16x8 af, bfr;
    af[0] = (__bf16)a0.x; af[1] = (__bf16)a0.y; af[2] = (__bf16)a0.z; af[3] = (__bf16)a0.w;
    af[4] = (__bf16)a1.x; af[5] = (__bf16)a1.y; af[6] = (__bf16)a1.z; af[7] = (__bf16)a1.w;
    bfr[0] = (__bf16)pp[0 * NK]; bfr[1] = (__bf16)pp[1 * NK];
    bfr[2] = (__bf16)pp[2 * NK]; bfr[3] = (__bf16)pp[3 * NK];
    bfr[4] = (__bf16)pp[4 * NK]; bfr[5] = (__bf16)pp[5 * NK];
    bfr[6] = (__bf16)pp[6 * NK]; bfr[7] = (__bf16)pp[7 * NK];
    acc = __builtin_amdgcn_mfma_f32_16x16x32_bf16(af, bfr, acc, 0, 0, 0);
  }
#pragma unroll
  for (int r = 0; r < 4; ++r) {
    const int orow = m0 + g4 * 4 + r;   // C/D: col=lane&15, row=(lane>>4)*4+r (HW-verified)
    const float e = exp2f(c * acc[r]);
    const int p = __builtin_amdgcn_cvt_pk_fp8_f32(e, e, 0, false);
    E8[orow * NK + bcol] = (unsigned char)(p & 0xff);
  }
}

// first/stride are wave-uniform SGPR values; incremental (b,e) avoids per-iter div
__device__ __forceinline__ float edge_sum(
    const unsigned char* __restrict__ E8, const int* __restrict__ edges,
    const int m_edge, const int first, const int stride, const int lane) {
  const int ntask = NB * m_edge;
  float lsum = 0.0f;
  int b = first / m_edge;
  int e = first - b * m_edge;
  for (int task = first; task < ntask; task += stride) {
    const int v0 = edges[2 * e];
    const int v1 = edges[2 * e + 1];
    const size_t base = ((size_t)b << 18);
    const uint4 ua = ((const uint4*)(E8 + base + ((size_t)v0 << 10)))[lane];
    const uint4 ub = ((const uint4*)(E8 + base + ((size_t)v1 << 10)))[lane];
    float s0 = 0.f, s1 = 0.f;
    dot4_fp8(ua.x, ub.x, s0, s1);
    dot4_fp8(ua.y, ub.y, s0, s1);
    dot4_fp8(ua.z, ub.z, s0, s1);
    dot4_fp8(ua.w, ub.w, s0, s1);
    lsum += __logf(wave_reduce(s0 + s1));
    e += stride;
    if (e >= m_edge) { e -= m_edge; ++b; }   // stride < m_edge
  }
  return lsum;
}

__device__ __forceinline__ float tri_sum(
    const unsigned char* __restrict__ E8, const int* __restrict__ tris,
    const int m_tri, const int first, const int stride, const int lane) {
  const int ntask = NB * m_tri;
  float lsum = 0.0f;
  int b = first / m_tri;
  int e = first - b * m_tri;
  for (int task = first; task < ntask; task += stride) {
    const int v0 = tris[3 * e];
    const int v1 = tris[3 * e + 1];
    const int v2 = tris[3 * e + 2];
    const size_t base = ((size_t)b << 18);
    const uint4 ua = ((const uint4*)(E8 + base + ((size_t)v0 << 10)))[lane];
    const uint4 ub = ((const uint4*)(E8 + base + ((size_t)v1 << 10)))[lane];
    const uint4 uc = ((const uint4*)(E8 + base + ((size_t)v2 << 10)))[lane];
    float s0 = 0.f, s1 = 0.f;
    tdot4_fp8(ua.x, ub.x, uc.x, s0, s1);
    tdot4_fp8(ua.y, ub.y, uc.y, s0, s1);
    tdot4_fp8(ua.z, ub.z, uc.z, s0, s1);
    tdot4_fp8(ua.w, ub.w, uc.w, s0, s1);
    lsum += __logf(wave_reduce(s0 + s1));
    e += stride;
    if (e >= m_tri) { e -= m_tri; ++b; }     // stride < m_tri
  }
  return lsum;
}

// K1: gemm+exp->fp8 (blocks 0..1023, REP1 internal repeats for rocprof
// visibility — identical stores each rep) + g2 partials (blocks 1024..1055)
__global__ __launch_bounds__(256) void gemm_exp_g2_kernel(
    const float* __restrict__ A, const float* __restrict__ P,
    const float* __restrict__ beta, unsigned char* __restrict__ E8,
    float* __restrict__ pg2) {
  const int lane = threadIdx.x & 63;
  const int w = threadIdx.x >> 6;
  const int bid = blockIdx.x;
  if (bid < 1024) {
    const float c = beta[0] * LOG2E;
    for (int r = 0; r < REP1; ++r) {
      gemm_tile(A, P, c, E8, bid, w, lane);
      asm volatile("" ::: "memory");   // keep each rep live (rule-17 guard)
    }
  } else {
    __shared__ float sp[4];
    const int gi = bid - 1024;
    float s = 0.0f;
    for (int i = gi * 256 + threadIdx.x; i < 65536; i += 32 * 256) {
      const float4 v = ((const float4*)A)[i];
      s += v.x * v.x + v.y * v.y + v.z * v.z + v.w * v.w;
    }
    s = wave_reduce(s);
    if (lane == 0) sp[w] = s;
    __syncthreads();
    if (threadIdx.x == 0) pg2[gi] = sp[0] + sp[1] + sp[2] + sp[3];
  }
}

// K2: edges + triangles, REP2 internal repeats (identical partials each rep)
__global__ __launch_bounds__(256, 8) void fused_simplex_kernel(
    const unsigned char* __restrict__ E8,
    const int* __restrict__ edges, const int m_edge,
    const int* __restrict__ tris, const int m_tri,
    float* __restrict__ pl) {
  __shared__ float sp[4];
  const int lane = threadIdx.x & 63;
  const int w = threadIdx.x >> 6;
  const int bid = blockIdx.x;

  if (bid < EDGE_BLOCKS) {
    const int first = __builtin_amdgcn_readfirstlane(bid * 4 + w);  // SGPR-hoist
    float lsum = 0.0f;
    for (int r = 0; r < REP2; ++r) {
      float t = edge_sum(E8, edges, m_edge, first, EDGE_BLOCKS * 4, lane);
      asm volatile("" : "+v"(t));      // opaque use: every rep stays live
      lsum = t;
    }
    if (lane == 0) sp[w] = lsum;
    __syncthreads();
    if (threadIdx.x == 0) pl[bid] = sp[0] + sp[1] + sp[2] + sp[3];
  } else {
    const int first = __builtin_amdgcn_readfirstlane((bid - EDGE_BLOCKS) * 4 + w);
    float lsum = 0.0f;
    for (int r = 0; r < REP2; ++r) {
      float t = tri_sum(E8, tris, m_tri, first, TRI_BLOCKS * 4, lane);
      asm volatile("" : "+v"(t));
      lsum = t;
    }
    if (lane == 0) sp[w] = lsum;
    __syncthreads();
    if (threadIdx.x == 0) pl[bid] = sp[0] + sp[1] + sp[2] + sp[3];
  }
}

// K3: single-block final reduction
__global__ __launch_bounds__(256) void final_kernel(
    const float* __restrict__ pl, const float* __restrict__ pg2,
    const float* __restrict__ beta, const int ns, float* __restrict__ out) {
  __shared__ float sa[4], sb[4];
  float sl = 0.f, sg = 0.f;
  for (int i = threadIdx.x; i < K2_BLOCKS; i += 256) sl += pl[i];
  if (threadIdx.x < 32) sg = pg2[threadIdx.x];
  sl = wave_reduce(sl);
  sg = wave_reduce(sg);
  const int lane = threadIdx.x & 63;
  const int w = threadIdx.x >> 6;
  if (lane == 0) { sa[w] = sl; sb[w] = sg; }
  __syncthreads();
  if (threadIdx.x == 0) {
    const float L = sa[0] + sa[1] + sa[2] + sa[3];
    const float Gg = sb[0] + sb[1] + sb[2] + sb[3];
    const float ep = -(1.0f / (beta[0] * (float)ns)) * L;
    out[0] = (ep - 2.0f * Gg) / (float)(NB * NN);
  }
}

extern "C" void kernel_launch(void* const* d_in, const int* in_sizes, int n_in,
                              void* d_out, int out_size, void* d_ws, size_t ws_size,
                              hipStream_t stream) {
  const float* g = (const float*)d_in[0];
  const float* patterns = (const float*)d_in[1];
  const float* beta = (const float*)d_in[2];
  const int* edges = (const int*)d_in[3];
  const int* triangles = (const int*)d_in[4];
  const int m_edge = in_sizes[3] / 2;   // 16320
  const int m_tri = in_sizes[4] / 3;    // 16320
  const int ns = m_edge + m_tri;

  // ws: E8 1MB | pl[2048] | pg2[32]
  unsigned char* E8 = (unsigned char*)d_ws;
  float* pl = (float*)((char*)d_ws + (1u << 20));
  float* pg2 = pl + K2_BLOCKS;
  float* out = (float*)d_out;

  hipLaunchKernelGGL(gemm_exp_g2_kernel, dim3(K1_BLOCKS), dim3(256), 0, stream,
                     g, patterns, beta, E8, pg2);
  hipLaunchKernelGGL(fused_simplex_kernel, dim3(K2_BLOCKS), dim3(256), 0, stream,
                     E8, edges, m_edge, triangles, m_tri, pl);
  hipLaunchKernelGGL(final_kernel, dim3(1), dim3(256), 0, stream,
                     pl, pg2, beta, ns, out);
}

// Round 8
// 36.170 us; speedup vs baseline: 6.1760x; 2.3159x over previous
//
#include <hip/hip_runtime.h>
#include <hip/hip_bf16.h>

#define NB 4
#define NN 256
#define ND 256
#define NK 1024
#define LOG2E 1.4426950408889634f

#define EDGE_BLOCKS 800
#define TRI_BLOCKS 1248
#define K2_BLOCKS (EDGE_BLOCKS + TRI_BLOCKS)   // 2048
#define K1_BLOCKS 1056                          // 1024 gemm tiles + 32 g2

typedef __bf16 bf16x8 __attribute__((ext_vector_type(8)));
typedef float f32x4 __attribute__((ext_vector_type(4)));
typedef float f32x2 __attribute__((ext_vector_type(2)));

// ---- fp8 helpers (OCP e4m3). f32x2 accumulators -> v_pk_mul/v_pk_fma_f32 ----
__device__ __forceinline__ void dot4_pk(unsigned a, unsigned b, f32x2& s) {
  const f32x2 a0 = __builtin_amdgcn_cvt_pk_f32_fp8(a, false);
  const f32x2 a1 = __builtin_amdgcn_cvt_pk_f32_fp8(a, true);
  const f32x2 b0 = __builtin_amdgcn_cvt_pk_f32_fp8(b, false);
  const f32x2 b1 = __builtin_amdgcn_cvt_pk_f32_fp8(b, true);
  s += a0 * b0;
  s += a1 * b1;
}

__device__ __forceinline__ void tdot4_pk(unsigned a, unsigned b, unsigned c, f32x2& s) {
  const f32x2 a0 = __builtin_amdgcn_cvt_pk_f32_fp8(a, false);
  const f32x2 a1 = __builtin_amdgcn_cvt_pk_f32_fp8(a, true);
  const f32x2 b0 = __builtin_amdgcn_cvt_pk_f32_fp8(b, false);
  const f32x2 b1 = __builtin_amdgcn_cvt_pk_f32_fp8(b, true);
  const f32x2 c0 = __builtin_amdgcn_cvt_pk_f32_fp8(c, false);
  const f32x2 c1 = __builtin_amdgcn_cvt_pk_f32_fp8(c, true);
  s += (a0 * b0) * c0;   // pk_mul + pk_fma
  s += (a1 * b1) * c1;
}

__device__ __forceinline__ float wave_reduce(float s) {
#pragma unroll
  for (int m = 32; m >= 1; m >>= 1) s += __shfl_xor(s, m, 64);
  return s;
}

// reduce within a 16-lane group (masks 8..1 never cross the group boundary)
__device__ __forceinline__ float group16_reduce(float s) {
#pragma unroll
  for (int m = 8; m >= 1; m >>= 1) s += __shfl_xor(s, m, 64);
  return s;
}

// GEMM tile body: 16x64 tile (m-tile t>>4, n-group t&15), E8 = fp8(exp(beta*h))
__device__ __forceinline__ void gemm_tile(
    const float* __restrict__ A, const float* __restrict__ P, const float c,
    unsigned char* __restrict__ E8, const int t, const int w, const int lane) {
  const int m0 = (t >> 4) * 16;
  const int n0 = (t & 15) * 64 + w * 16;
  const int r15 = lane & 15;
  const int g4 = lane >> 4;
  const int arow = m0 + r15;
  const int bcol = n0 + r15;

  f32x4 acc = {0.f, 0.f, 0.f, 0.f};
#pragma unroll
  for (int kk = 0; kk < ND; kk += 32) {
    const int kb = kk + g4 * 8;  // same (group,elem)->k map for A and B => layout-safe
    const float* ap = A + arow * ND + kb;
    const float4 a0 = *(const float4*)ap;
    const float4 a1 = *(const float4*)(ap + 4);
    const float* pp = P + kb * NK + bcol;
    bf16x8 af, bfr;
    af[0] = (__bf16)a0.x; af[1] = (__bf16)a0.y; af[2] = (__bf16)a0.z; af[3] = (__bf16)a0.w;
    af[4] = (__bf16)a1.x; af[5] = (__bf16)a1.y; af[6] = (__bf16)a1.z; af[7] = (__bf16)a1.w;
    bfr[0] = (__bf16)pp[0 * NK]; bfr[1] = (__bf16)pp[1 * NK];
    bfr[2] = (__bf16)pp[2 * NK]; bfr[3] = (__bf16)pp[3 * NK];
    bfr[4] = (__bf16)pp[4 * NK]; bfr[5] = (__bf16)pp[5 * NK];
    bfr[6] = (__bf16)pp[6 * NK]; bfr[7] = (__bf16)pp[7 * NK];
    acc = __builtin_amdgcn_mfma_f32_16x16x32_bf16(af, bfr, acc, 0, 0, 0);
  }
#pragma unroll
  for (int r = 0; r < 4; ++r) {
    const int orow = m0 + g4 * 4 + r;   // C/D: col=lane&15, row=(lane>>4)*4+r (HW-verified)
    const float e = exp2f(c * acc[r]);
    const int p = __builtin_amdgcn_cvt_pk_fp8_f32(e, e, 0, false);
    E8[orow * NK + bcol] = (unsigned char)(p & 0xff);
  }
}

// K1: gemm+exp->fp8 (blocks 0..1023) + g2 partials (blocks 1024..1055)
__global__ __launch_bounds__(256) void gemm_exp_g2_kernel(
    const float* __restrict__ A, const float* __restrict__ P,
    const float* __restrict__ beta, unsigned char* __restrict__ E8,
    float* __restrict__ pg2) {
  const int lane = threadIdx.x & 63;
  const int w = threadIdx.x >> 6;
  const int bid = blockIdx.x;
  if (bid < 1024) {
    gemm_tile(A, P, beta[0] * LOG2E, E8, bid, w, lane);
  } else {
    __shared__ float sp[4];
    const int gi = bid - 1024;
    float s = 0.0f;
    for (int i = gi * 256 + threadIdx.x; i < 65536; i += 32 * 256) {
      const float4 v = ((const float4*)A)[i];
      s += v.x * v.x + v.y * v.y + v.z * v.z + v.w * v.w;
    }
    s = wave_reduce(s);
    if (lane == 0) sp[w] = s;
    __syncthreads();
    if (threadIdx.x == 0) pg2[gi] = sp[0] + sp[1] + sp[2] + sp[3];
  }
}

// K2: edges + triangles. One task per 16-lane group (4 tasks/wave).
__global__ __launch_bounds__(256, 6) void fused_simplex_kernel(
    const unsigned char* __restrict__ E8,
    const int* __restrict__ edges, const int m_edge,
    const int* __restrict__ tris, const int m_tri,
    float* __restrict__ pl) {
  __shared__ float sp[4];
  const int lane = threadIdx.x & 63;
  const int w = threadIdx.x >> 6;
  const int grp = lane >> 4;
  const int sub = lane & 15;
  const int bid = blockIdx.x;
  float lsum = 0.0f;

  if (bid < EDGE_BLOCKS) {
    const int stride = EDGE_BLOCKS * 16;       // 12800 < m_edge
    const int ntask = NB * m_edge;
    const int slot = bid * 16 + w * 4 + grp;
    int b = slot / m_edge;
    int e = slot - b * m_edge;
    for (int task = slot; task < ntask; task += stride) {
      const int2 v01 = *(const int2*)(edges + 2 * e);   // 8B-aligned
      const uint4* r0 = (const uint4*)(E8 + ((size_t)b << 18) + ((size_t)v01.x << 10));
      const uint4* r1 = (const uint4*)(E8 + ((size_t)b << 18) + ((size_t)v01.y << 10));
      f32x2 s2 = {0.f, 0.f};
#pragma unroll
      for (int j = 0; j < 4; ++j) {
        const uint4 ua = r0[sub + j * 16];    // 16 lanes x 16B = 256B contiguous
        const uint4 ub = r1[sub + j * 16];
        dot4_pk(ua.x, ub.x, s2);
        dot4_pk(ua.y, ub.y, s2);
        dot4_pk(ua.z, ub.z, s2);
        dot4_pk(ua.w, ub.w, s2);
      }
      lsum += __logf(group16_reduce(s2[0] + s2[1]));   // identical in all 16 lanes
      e += stride;
      if (e >= m_edge) { e -= m_edge; ++b; }
    }
  } else {
    const int stride = TRI_BLOCKS * 16;        // 19968 > m_tri: double-wrap handled
    const int ntask = NB * m_tri;
    const int slot = (bid - EDGE_BLOCKS) * 16 + w * 4 + grp;
    int b = slot / m_tri;
    int e = slot - b * m_tri;
    for (int task = slot; task < ntask; task += stride) {
      const int v0 = tris[3 * e];
      const int v1 = tris[3 * e + 1];
      const int v2 = tris[3 * e + 2];
      const uint4* r0 = (const uint4*)(E8 + ((size_t)b << 18) + ((size_t)v0 << 10));
      const uint4* r1 = (const uint4*)(E8 + ((size_t)b << 18) + ((size_t)v1 << 10));
      const uint4* r2 = (const uint4*)(E8 + ((size_t)b << 18) + ((size_t)v2 << 10));
      f32x2 s2 = {0.f, 0.f};
#pragma unroll
      for (int j = 0; j < 4; ++j) {
        const uint4 ua = r0[sub + j * 16];
        const uint4 ub = r1[sub + j * 16];
        const uint4 uc = r2[sub + j * 16];
        tdot4_pk(ua.x, ub.x, uc.x, s2);
        tdot4_pk(ua.y, ub.y, uc.y, s2);
        tdot4_pk(ua.z, ub.z, uc.z, s2);
        tdot4_pk(ua.w, ub.w, uc.w, s2);
      }
      lsum += __logf(group16_reduce(s2[0] + s2[1]));
      e += stride - m_tri; ++b;                 // stride in (m_tri, 2*m_tri)
      if (e >= m_tri) { e -= m_tri; ++b; }
    }
  }

  lsum *= 0.0625f;                              // each group's log counted 16x
  lsum = wave_reduce(lsum);
  if (lane == 0) sp[w] = lsum;
  __syncthreads();
  if (threadIdx.x == 0) pl[bid] = sp[0] + sp[1] + sp[2] + sp[3];
}

// K3: single-block final reduction
__global__ __launch_bounds__(256) void final_kernel(
    const float* __restrict__ pl, const float* __restrict__ pg2,
    const float* __restrict__ beta, const int ns, float* __restrict__ out) {
  __shared__ float sa[4], sb[4];
  float sl = 0.f, sg = 0.f;
  for (int i = threadIdx.x; i < K2_BLOCKS; i += 256) sl += pl[i];
  if (threadIdx.x < 32) sg = pg2[threadIdx.x];
  sl = wave_reduce(sl);
  sg = wave_reduce(sg);
  const int lane = threadIdx.x & 63;
  const int w = threadIdx.x >> 6;
  if (lane == 0) { sa[w] = sl; sb[w] = sg; }
  __syncthreads();
  if (threadIdx.x == 0) {
    const float L = sa[0] + sa[1] + sa[2] + sa[3];
    const float Gg = sb[0] + sb[1] + sb[2] + sb[3];
    const float ep = -(1.0f / (beta[0] * (float)ns)) * L;
    out[0] = (ep - 2.0f * Gg) / (float)(NB * NN);
  }
}

extern "C" void kernel_launch(void* const* d_in, const int* in_sizes, int n_in,
                              void* d_out, int out_size, void* d_ws, size_t ws_size,
                              hipStream_t stream) {
  const float* g = (const float*)d_in[0];
  const float* patterns = (const float*)d_in[1];
  const float* beta = (const float*)d_in[2];
  const int* edges = (const int*)d_in[3];
  const int* triangles = (const int*)d_in[4];
  const int m_edge = in_sizes[3] / 2;   // 16320
  const int m_tri = in_sizes[4] / 3;    // 16320
  const int ns = m_edge + m_tri;

  // ws: E8 1MB | pl[2048] | pg2[32]
  unsigned char* E8 = (unsigned char*)d_ws;
  float* pl = (float*)((char*)d_ws + (1u << 20));
  float* pg2 = pl + K2_BLOCKS;
  float* out = (float*)d_out;

  hipLaunchKernelGGL(gemm_exp_g2_kernel, dim3(K1_BLOCKS), dim3(256), 0, stream,
                     g, patterns, beta, E8, pg2);
  hipLaunchKernelGGL(fused_simplex_kernel, dim3(K2_BLOCKS), dim3(256), 0, stream,
                     E8, edges, m_edge, triangles, m_tri, pl);
  hipLaunchKernelGGL(final_kernel, dim3(1), dim3(256), 0, stream,
                     pl, pg2, beta, ns, out);
}